// Round 3
// baseline (275.619 us; speedup 1.0000x reference)
//
#include <hip/hip_runtime.h>
#include <math.h>

// NetVLAD, MFMA split-bf16 + vmcnt-open pipelined staging.
// Sizes fixed: N=64, C=128, P=4096, K=64.
#define NNIMG 64
#define CCH 128
#define KK 64
#define PP 4096
#define BSPLIT 8
#define PB (PP / BSPLIT)   // 512 pixels per block
#define PC 64              // pixels per chunk
#define NCHUNK (PB / PC)   // 8

typedef __attribute__((ext_vector_type(8))) short short8;
typedef __attribute__((ext_vector_type(4))) float f32x4;

__device__ __forceinline__ unsigned short bf16_hi(float f) {
  unsigned u = __float_as_uint(f);
  unsigned r = u + 0x7FFFu + ((u >> 16) & 1u);  // RTNE
  return (unsigned short)(r >> 16);
}
__device__ __forceinline__ float bf16_tof(unsigned short h) {
  return __uint_as_float(((unsigned)h) << 16);
}
// pack (hi = RTNE bf16 of f) | (lo = trunc bf16 of f-hi) << 16
__device__ __forceinline__ unsigned pack_hl(float f) {
  unsigned u = __float_as_uint(f);
  unsigned r = u + 0x7FFFu + ((u >> 16) & 1u);
  float hf = __uint_as_float(r & 0xFFFF0000u);
  unsigned lo = __float_as_uint(f - hf);
  return __builtin_amdgcn_perm(lo, r, 0x07060302u);  // r[31:16] low, lo[31:16] high
}

// barrier with LDS visibility but WITHOUT draining vmcnt — keeps global
// prefetch loads in flight across the barrier (AITER-style pipeline).
__device__ __forceinline__ void lgkm_barrier() {
  __asm__ volatile("s_waitcnt lgkmcnt(0)\n\ts_barrier" ::: "memory");
}

// LDS (44288 B -> 3 blocks/CU capacity; grid gives 2/CU):
//  pc_hl : u32 [p=64][c stride 132] (hi|lo<<16), c XOR-swizzled 8*((p>>2)&3)  33792 B
//  a_lds : u16 [k=64][p stride 72]  assignments bf16                           9216 B
//  b_lds f32[64] + asum_buf f32[256]                                           1280 B
__global__ __launch_bounds__(256, 2) void netvlad_main(
    const float* __restrict__ x, const float* __restrict__ conv_w,
    const float* __restrict__ conv_b, float* __restrict__ vlad_part,
    float* __restrict__ asum_part) {
  __shared__ unsigned int pc_hl[PC * 132];
  __shared__ unsigned short a_lds[KK * 72];
  __shared__ float b_lds[KK];
  __shared__ float asum_buf[4 * KK];

  const int t = threadIdx.x;
  const int lane = t & 63;
  const int wv = t >> 6;      // wave 0..3
  const int m = lane & 15;
  const int q = lane >> 4;

  const int n = blockIdx.x / BSPLIT;
  const int blk = blockIdx.x % BSPLIT;

  if (t < KK) b_lds[t] = conv_b[t];

  // ---- W fragments (hi + lo), A-operand layout A[m][c=q*8+j] ----
  short8 Whi[4][4], Wlo[4][4];
#pragma unroll
  for (int kt = 0; kt < 4; ++kt) {
#pragma unroll
    for (int cs = 0; cs < 4; ++cs) {
      const float* wp = conv_w + (kt * 16 + m) * CCH + cs * 32 + q * 8;
      float4 wa = *(const float4*)wp;
      float4 wb = *(const float4*)(wp + 4);
      float fv[8] = {wa.x, wa.y, wa.z, wa.w, wb.x, wb.y, wb.z, wb.w};
      short8 h, l;
#pragma unroll
      for (int j = 0; j < 8; ++j) {
        unsigned short hb = bf16_hi(fv[j]);
        h[j] = (short)hb;
        l[j] = (short)bf16_hi(fv[j] - bf16_tof(hb));
      }
      Whi[kt][cs] = h;
      Wlo[kt][cs] = l;
    }
  }

  f32x4 vacc[4][2];
#pragma unroll
  for (int kt = 0; kt < 4; ++kt)
#pragma unroll
    for (int ct = 0; ct < 2; ++ct) vacc[kt][ct] = (f32x4){0.f, 0.f, 0.f, 0.f};
  float asum_acc[16];
#pragma unroll
  for (int i = 0; i < 16; ++i) asum_acc[i] = 0.f;

  const int crow = t >> 3;        // staging: c row (+32*ci)
  const int pr = t & 7;           // staging: float4 granule along p
  const int prow = wv * 16 + m;   // this lane's pixel column within chunk
  const int swz_r = 8 * ((prow >> 2) & 3);
  const float* xbase = x + (size_t)n * CCH * PP + blk * PB;

  // body: prefetch chunk(nb) into nxt, stage cur, GEMM1+softmax, GEMM2.
  auto body = [&](float4 (&cur)[8], float4 (&nxt)[8], const float* nb) {
    // 1. issue next chunk's global loads (consumed next call; vmcnt stays open)
#pragma unroll
    for (int ci = 0; ci < 4; ++ci)
#pragma unroll
      for (int rep = 0; rep < 2; ++rep)
        nxt[ci * 2 + rep] =
            *(const float4*)(nb + (size_t)(crow + ci * 32) * PP + pr * 4 + rep * 32);

    // 2. stage cur -> pc_hl [p][c^swz] packed hi|lo
#pragma unroll
    for (int ci = 0; ci < 4; ++ci) {
      int cc = (crow + ci * 32) ^ (8 * (pr & 3));
#pragma unroll
      for (int rep = 0; rep < 2; ++rep) {
        int pl = pr * 4 + rep * 32;
        float4 v = cur[ci * 2 + rep];
        float fv[4] = {v.x, v.y, v.z, v.w};
#pragma unroll
        for (int j = 0; j < 4; ++j) pc_hl[(pl + j) * 132 + cc] = pack_hl(fv[j]);
      }
    }
    lgkm_barrier();  // B1: pc_hl published

    // 3a. GEMM1: logits[k=64][p = prow], 3-term split bf16
    f32x4 acc1[4];
#pragma unroll
    for (int kt = 0; kt < 4; ++kt) acc1[kt] = (f32x4){0.f, 0.f, 0.f, 0.f};
    const unsigned int* pcrow = pc_hl + prow * 132;
#pragma unroll
    for (int cs = 0; cs < 4; ++cs) {
      int base = cs * 32 + ((q << 3) ^ swz_r);
      uint4 s0 = *(const uint4*)&pcrow[base];
      uint4 s1 = *(const uint4*)&pcrow[base + 4];
      unsigned int ss[8] = {s0.x, s0.y, s0.z, s0.w, s1.x, s1.y, s1.z, s1.w};
      unsigned int hs[4], ls[4];
#pragma unroll
      for (int i = 0; i < 4; ++i) {
        hs[i] = __builtin_amdgcn_perm(ss[2 * i + 1], ss[2 * i], 0x05040100u);
        ls[i] = __builtin_amdgcn_perm(ss[2 * i + 1], ss[2 * i], 0x07060302u);
      }
      short8 Bh, Bl;
      __builtin_memcpy(&Bh, hs, 16);
      __builtin_memcpy(&Bl, ls, 16);
#pragma unroll
      for (int kt = 0; kt < 4; ++kt) {
        acc1[kt] = __builtin_amdgcn_mfma_f32_16x16x32_bf16(Whi[kt][cs], Bh, acc1[kt], 0, 0, 0);
        acc1[kt] = __builtin_amdgcn_mfma_f32_16x16x32_bf16(Whi[kt][cs], Bl, acc1[kt], 0, 0, 0);
        acc1[kt] = __builtin_amdgcn_mfma_f32_16x16x32_bf16(Wlo[kt][cs], Bh, acc1[kt], 0, 0, 0);
      }
    }

    // 3b. gather GEMM2 B-frags from pc_hl NOW (pre-B2; pc_hl is dead after)
    unsigned int bg[4][4];  // [ct*2+ps][4 u32 of packed bf16 hi]
#pragma unroll
    for (int ct = 0; ct < 2; ++ct)
#pragma unroll
      for (int ps = 0; ps < 2; ++ps) {
        int c = wv * 32 + ct * 16 + m;
        unsigned int g[8];
#pragma unroll
        for (int j = 0; j < 8; ++j) {
          int p = ps * 32 + q * 8 + j;
          g[j] = pc_hl[p * 132 + (c ^ (8 * ((p >> 2) & 3)))];
        }
#pragma unroll
        for (int i = 0; i < 4; ++i)
          bg[ct * 2 + ps][i] = __builtin_amdgcn_perm(g[2 * i + 1], g[2 * i], 0x05040100u);
      }

    // 3c. softmax over k (register-resident; lane holds 16 of 64 k)
    float ssum = 0.f;
#pragma unroll
    for (int kt = 0; kt < 4; ++kt)
#pragma unroll
      for (int r = 0; r < 4; ++r) {
        float e = __expf(acc1[kt][r] + b_lds[kt * 16 + q * 4 + r]);
        acc1[kt][r] = e;
        ssum += e;
      }
    ssum += __shfl_xor(ssum, 16, 64);
    ssum += __shfl_xor(ssum, 32, 64);
    float inv = 1.0f / ssum;
#pragma unroll
    for (int kt = 0; kt < 4; ++kt)
#pragma unroll
      for (int r = 0; r < 4; ++r) {
        float a = acc1[kt][r] * inv;
        asum_acc[kt * 4 + r] += a;
        a_lds[(kt * 16 + q * 4 + r) * 72 + prow] = bf16_hi(a);
      }
    lgkm_barrier();  // B2: a_lds published; pc_hl reads all complete

    // 4. GEMM2: V[k][c] += A[k][p] * X^T[p][c]
#pragma unroll
    for (int ps = 0; ps < 2; ++ps) {
      short8 Af[4];
#pragma unroll
      for (int kt = 0; kt < 4; ++kt)
        Af[kt] = *(const short8*)&a_lds[(kt * 16 + m) * 72 + ps * 32 + q * 8];
#pragma unroll
      for (int ct = 0; ct < 2; ++ct) {
        short8 Bf;
        __builtin_memcpy(&Bf, bg[ct * 2 + ps], 16);
#pragma unroll
        for (int kt = 0; kt < 4; ++kt)
          vacc[kt][ct] = __builtin_amdgcn_mfma_f32_16x16x32_bf16(Af[kt], Bf, vacc[kt][ct], 0, 0, 0);
      }
    }
  };

  float4 bufA[8], bufB[8];
  // prologue: load chunk 0
#pragma unroll
  for (int ci = 0; ci < 4; ++ci)
#pragma unroll
    for (int rep = 0; rep < 2; ++rep)
      bufA[ci * 2 + rep] =
          *(const float4*)(xbase + (size_t)(crow + ci * 32) * PP + pr * 4 + rep * 32);

#pragma unroll 1
  for (int ch = 0; ch < NCHUNK; ch += 2) {
    body(bufA, bufB, xbase + (ch + 1) * PC);
    body(bufB, bufA, xbase + ((ch + 2) & (NCHUNK - 1)) * PC);  // last: dummy reload of ch0
  }

  // ---- epilogue: transpose vacc through (dead) pc_hl, coalesced float4 out ----
  float* vt = (float*)pc_hl;  // [k=64][c stride 132]
#pragma unroll
  for (int kt = 0; kt < 4; ++kt)
#pragma unroll
    for (int ct = 0; ct < 2; ++ct)
#pragma unroll
      for (int r = 0; r < 4; ++r)
        vt[(kt * 16 + q * 4 + r) * 132 + wv * 32 + ct * 16 + m] = vacc[kt][ct][r];
#pragma unroll
  for (int i = 0; i < 16; ++i) {
    float v = asum_acc[i];
    v += __shfl_xor(v, 1, 64);
    v += __shfl_xor(v, 2, 64);
    v += __shfl_xor(v, 4, 64);
    v += __shfl_xor(v, 8, 64);
    if (m == 0) asum_buf[wv * 64 + (i >> 2) * 16 + q * 4 + (i & 3)] = v;
  }
  lgkm_barrier();
  {
    const int k = t >> 2, c0 = (t & 3) * 32;
    const size_t ob = (size_t)blockIdx.x * (KK * CCH) + k * CCH + c0;
#pragma unroll
    for (int i = 0; i < 8; ++i)
      *(float4*)&vlad_part[ob + i * 4] = *(const float4*)&vt[k * 132 + c0 + i * 4];
  }
  if (t < 64) {
    float s = asum_buf[t] + asum_buf[64 + t] + asum_buf[128 + t] + asum_buf[192 + t];
    asum_part[blockIdx.x * 64 + t] = s;
  }
}

// One wave per (n,k): sum 8 partials, subtract asum*centroid, per-cluster L2 norm.
// Global norm over the 64 unit per-cluster vectors is exactly sqrt(64) -> x0.125.
__global__ __launch_bounds__(256) void netvlad_finish(
    const float* __restrict__ vlad_part, const float* __restrict__ asum_part,
    const float* __restrict__ centroids, float* __restrict__ out) {
  const int t = threadIdx.x;
  const int w = t >> 6, ln = t & 63;
  const int idx = blockIdx.x * 4 + w;  // 0..4095
  const int n = idx >> 6, k = idx & 63;
  const int c = ln * 2;
  float v0 = 0.f, v1 = 0.f;
#pragma unroll
  for (int b = 0; b < BSPLIT; ++b) {
    float2 pv = *(const float2*)&vlad_part[(size_t)(n * BSPLIT + b) * (KK * CCH) + k * CCH + c];
    v0 += pv.x;
    v1 += pv.y;
  }
  float s = 0.f;
#pragma unroll
  for (int b = 0; b < BSPLIT; ++b) s += asum_part[(n * BSPLIT + b) * KK + k];
  float2 ce = *(const float2*)&centroids[k * CCH + c];
  v0 -= s * ce.x;
  v1 -= s * ce.y;
  float ssq = v0 * v0 + v1 * v1;
#pragma unroll
  for (int off = 32; off > 0; off >>= 1) ssq += __shfl_xor(ssq, off, 64);
  float inv = 0.125f / fmaxf(sqrtf(ssq), 1e-12f);
  float2 o;
  o.x = v0 * inv;
  o.y = v1 * inv;
  *(float2*)&out[(size_t)n * (KK * CCH) + k * CCH + c] = o;
}

extern "C" void kernel_launch(void* const* d_in, const int* in_sizes, int n_in,
                              void* d_out, int out_size, void* d_ws, size_t ws_size,
                              hipStream_t stream) {
  const float* x = (const float*)d_in[0];          // (64,128,64,64)
  const float* conv_w = (const float*)d_in[1];     // (64,128)
  const float* conv_b = (const float*)d_in[2];     // (64,)
  const float* centroids = (const float*)d_in[3];  // (64,128)
  float* out = (float*)d_out;                      // (64, 8192)

  float* vlad_part = (float*)d_ws;                                   // 16 MiB
  float* asum_part = vlad_part + (size_t)NNIMG * BSPLIT * KK * CCH;  // 128 KiB

  netvlad_main<<<NNIMG * BSPLIT, 256, 0, stream>>>(x, conv_w, conv_b, vlad_part, asum_part);
  netvlad_finish<<<NNIMG * KK / 4, 256, 0, stream>>>(vlad_part, asum_part, centroids, out);
}

// Round 4
// 237.750 us; speedup vs baseline: 1.1593x; 1.1593x over previous
//
#include <hip/hip_runtime.h>
#include <math.h>

// NetVLAD, MFMA split-bf16 + LDS-DMA pipelined staging (global_load_lds).
// Sizes fixed: N=64, C=128, P=4096, K=64.
#define NNIMG 64
#define CCH 128
#define KK 64
#define PP 4096
#define BSPLIT 8
#define PB (PP / BSPLIT)   // 512 pixels per block
#define PC 64              // pixels per chunk
#define NCHUNK (PB / PC)   // 8

typedef __attribute__((ext_vector_type(8))) short short8;
typedef __attribute__((ext_vector_type(4))) float f32x4;

__device__ __forceinline__ unsigned short bf16_hi(float f) {
  unsigned u = __float_as_uint(f);
  unsigned r = u + 0x7FFFu + ((u >> 16) & 1u);  // RTNE
  return (unsigned short)(r >> 16);
}
__device__ __forceinline__ float bf16_tof(unsigned short h) {
  return __uint_as_float(((unsigned)h) << 16);
}
// pack (hi = RTNE bf16 of f) | (bf16 of residual f-hi) << 16
__device__ __forceinline__ unsigned pack_hl(float f) {
  unsigned u = __float_as_uint(f);
  unsigned r = u + 0x7FFFu + ((u >> 16) & 1u);
  float hf = __uint_as_float(r & 0xFFFF0000u);
  unsigned lo = __float_as_uint(f - hf);
  return __builtin_amdgcn_perm(lo, r, 0x07060302u);  // r[31:16] low half, lo[31:16] high half
}

// barrier with LDS visibility but WITHOUT draining vmcnt — in-flight
// global_load_lds DMA stays open across it.
__device__ __forceinline__ void lgkm_barrier() {
  __asm__ volatile("s_waitcnt lgkmcnt(0)\n\ts_barrier" ::: "memory");
}
// top-of-chunk: wait own DMA landed, then all-wave barrier.
__device__ __forceinline__ void vm_barrier() {
  __asm__ volatile("s_waitcnt vmcnt(0)\n\ts_barrier" ::: "memory");
}

// async 16B/lane global->LDS; lds base must be wave-uniform (dest = base + lane*16).
__device__ __forceinline__ void load_to_lds16(const float* g, float* l) {
  __builtin_amdgcn_global_load_lds((const __attribute__((address_space(1))) void*)g,
                                   (__attribute__((address_space(3))) void*)l, 16, 0, 0);
}

// LDS (77056 B -> 2 blocks/CU):
//  xraw  : f32 [c=128][p=64] contiguous (DMA dest)                    32768 B
//  pc_hl : u32 [p=64][c stride 132] (hi|lo), c XOR-swz 8*((p>>2)&3)   33792 B
//  a_lds : u16 [k=64][p stride 72]  assignments bf16                   9216 B
//  b_lds f32[64] + asum_buf f32[256]                                   1280 B
__global__ __launch_bounds__(256, 2) void netvlad_main(
    const float* __restrict__ x, const float* __restrict__ conv_w,
    const float* __restrict__ conv_b, float* __restrict__ vlad_part,
    float* __restrict__ asum_part) {
  __shared__ __align__(16) float xraw[CCH * PC];
  __shared__ __align__(16) unsigned int pc_hl[PC * 132];
  __shared__ __align__(16) unsigned short a_lds[KK * 72];
  __shared__ float b_lds[KK];
  __shared__ float asum_buf[4 * KK];

  const int t = threadIdx.x;
  const int lane = t & 63;
  const int wv = t >> 6;      // wave 0..3
  const int m = lane & 15;
  const int q = lane >> 4;

  const int n = blockIdx.x / BSPLIT;
  const int blk = blockIdx.x % BSPLIT;
  const float* xbase = x + (size_t)n * CCH * PP + blk * PB;

  // DMA one chunk: wave wv covers c rows 32wv..32wv+31 via 8 instructions.
  auto issue_dma = [&](int ch) {
#pragma unroll
    for (int i = 0; i < 8; ++i) {
      int row = 8 * wv + i;  // 4 c-rows per instruction
      const float* g =
          xbase + (size_t)(4 * row + (lane >> 4)) * PP + ch * PC + (lane & 15) * 4;
      load_to_lds16(g, &xraw[row * 256]);
    }
  };

  issue_dma(0);  // prologue prefetch (covered by W-frag setup below)

  if (t < KK) b_lds[t] = conv_b[t];

  // ---- W fragments (hi + lo), A-operand layout A[m][c=q*8+j] ----
  short8 Whi[4][4], Wlo[4][4];
#pragma unroll
  for (int kt = 0; kt < 4; ++kt) {
#pragma unroll
    for (int cs = 0; cs < 4; ++cs) {
      const float* wp = conv_w + (kt * 16 + m) * CCH + cs * 32 + q * 8;
      float4 wa = *(const float4*)wp;
      float4 wb = *(const float4*)(wp + 4);
      float fv[8] = {wa.x, wa.y, wa.z, wa.w, wb.x, wb.y, wb.z, wb.w};
      short8 h, l;
#pragma unroll
      for (int j = 0; j < 8; ++j) {
        unsigned short hb = bf16_hi(fv[j]);
        h[j] = (short)hb;
        l[j] = (short)bf16_hi(fv[j] - bf16_tof(hb));
      }
      Whi[kt][cs] = h;
      Wlo[kt][cs] = l;
    }
  }

  f32x4 vacc[4][2];
#pragma unroll
  for (int kt = 0; kt < 4; ++kt)
#pragma unroll
    for (int ct = 0; ct < 2; ++ct) vacc[kt][ct] = (f32x4){0.f, 0.f, 0.f, 0.f};
  float asum_acc[16];
#pragma unroll
  for (int i = 0; i < 16; ++i) asum_acc[i] = 0.f;

  const int crow = t >> 3;        // stage: c row (+32*ci); per wave 8 rows
  const int pr = t & 7;           // stage: float4 granule along p
  const int prow = wv * 16 + m;   // GEMM1: lane's pixel column in chunk
  const int swz_r = 8 * ((prow >> 2) & 3);

#pragma unroll 1
  for (int ch = 0; ch < NCHUNK; ++ch) {
    vm_barrier();  // DMA(ch) landed for every wave

    // ---- stage: xraw [c][p] (ds_read_b128, conflict-free) -> pack -> pc_hl ----
#pragma unroll
    for (int ci = 0; ci < 4; ++ci) {
      int c = crow + ci * 32;
      int cc = c ^ (8 * (pr & 3));
#pragma unroll
      for (int rep = 0; rep < 2; ++rep) {
        int pl = pr * 4 + rep * 32;
        float4 v = *(const float4*)&xraw[c * 64 + pl];
        float fv[4] = {v.x, v.y, v.z, v.w};
#pragma unroll
        for (int j = 0; j < 4; ++j) pc_hl[(pl + j) * 132 + cc] = pack_hl(fv[j]);
      }
    }
    lgkm_barrier();  // B1: pc_hl published; all xraw reads drained

    if (ch < NCHUNK - 1) issue_dma(ch + 1);  // overwrites xraw; lands during GEMMs

    // ---- GEMM1: logits[k=64][p=prow], 3-term split bf16 ----
    f32x4 acc1[4];
#pragma unroll
    for (int kt = 0; kt < 4; ++kt) acc1[kt] = (f32x4){0.f, 0.f, 0.f, 0.f};
    const unsigned int* pcrow = pc_hl + prow * 132;
#pragma unroll
    for (int cs = 0; cs < 4; ++cs) {
      int base = cs * 32 + ((q << 3) ^ swz_r);
      uint4 s0 = *(const uint4*)&pcrow[base];
      uint4 s1 = *(const uint4*)&pcrow[base + 4];
      unsigned int ss[8] = {s0.x, s0.y, s0.z, s0.w, s1.x, s1.y, s1.z, s1.w};
      unsigned int hs[4], ls[4];
#pragma unroll
      for (int i = 0; i < 4; ++i) {
        hs[i] = __builtin_amdgcn_perm(ss[2 * i + 1], ss[2 * i], 0x05040100u);
        ls[i] = __builtin_amdgcn_perm(ss[2 * i + 1], ss[2 * i], 0x07060302u);
      }
      short8 Bh, Bl;
      __builtin_memcpy(&Bh, hs, 16);
      __builtin_memcpy(&Bl, ls, 16);
#pragma unroll
      for (int kt = 0; kt < 4; ++kt) {
        acc1[kt] = __builtin_amdgcn_mfma_f32_16x16x32_bf16(Whi[kt][cs], Bh, acc1[kt], 0, 0, 0);
        acc1[kt] = __builtin_amdgcn_mfma_f32_16x16x32_bf16(Whi[kt][cs], Bl, acc1[kt], 0, 0, 0);
        acc1[kt] = __builtin_amdgcn_mfma_f32_16x16x32_bf16(Wlo[kt][cs], Bh, acc1[kt], 0, 0, 0);
      }
    }

    // ---- softmax over k (register-resident; lane holds 16 of 64 k) ----
    float ssum = 0.f;
#pragma unroll
    for (int kt = 0; kt < 4; ++kt)
#pragma unroll
      for (int r = 0; r < 4; ++r) {
        float e = __expf(acc1[kt][r] + b_lds[kt * 16 + q * 4 + r]);
        acc1[kt][r] = e;
        ssum += e;
      }
    ssum += __shfl_xor(ssum, 16, 64);
    ssum += __shfl_xor(ssum, 32, 64);
    float inv = 1.0f / ssum;
#pragma unroll
    for (int kt = 0; kt < 4; ++kt)
#pragma unroll
      for (int r = 0; r < 4; ++r) {
        float a = acc1[kt][r] * inv;
        asum_acc[kt * 4 + r] += a;
        a_lds[(kt * 16 + q * 4 + r) * 72 + prow] = bf16_hi(a);
      }
    lgkm_barrier();  // B2: a_lds published

    // ---- GEMM2: V[k][c] += A[k][p] * X^T[p][c]  (B gathered from pc_hl) ----
#pragma unroll
    for (int ps = 0; ps < 2; ++ps) {
      short8 Af[4];
#pragma unroll
      for (int kt = 0; kt < 4; ++kt)
        Af[kt] = *(const short8*)&a_lds[(kt * 16 + m) * 72 + ps * 32 + q * 8];
#pragma unroll
      for (int ct = 0; ct < 2; ++ct) {
        int c = wv * 32 + ct * 16 + m;
        unsigned int g[8];
#pragma unroll
        for (int j = 0; j < 8; ++j) {
          int p = ps * 32 + q * 8 + j;
          g[j] = pc_hl[p * 132 + (c ^ (8 * ((p >> 2) & 3)))];
        }
        unsigned int hs[4];
#pragma unroll
        for (int i = 0; i < 4; ++i)
          hs[i] = __builtin_amdgcn_perm(g[2 * i + 1], g[2 * i], 0x05040100u);
        short8 Bf;
        __builtin_memcpy(&Bf, hs, 16);
#pragma unroll
        for (int kt = 0; kt < 4; ++kt)
          vacc[kt][ct] = __builtin_amdgcn_mfma_f32_16x16x32_bf16(Af[kt], Bf, vacc[kt][ct], 0, 0, 0);
      }
    }
  }

  // ---- epilogue: transpose vacc through (dead) pc_hl, coalesced float4 out ----
  float* vt = (float*)pc_hl;  // [k=64][c stride 132]
#pragma unroll
  for (int kt = 0; kt < 4; ++kt)
#pragma unroll
    for (int ct = 0; ct < 2; ++ct)
#pragma unroll
      for (int r = 0; r < 4; ++r)
        vt[(kt * 16 + q * 4 + r) * 132 + wv * 32 + ct * 16 + m] = vacc[kt][ct][r];
#pragma unroll
  for (int i = 0; i < 16; ++i) {
    float v = asum_acc[i];
    v += __shfl_xor(v, 1, 64);
    v += __shfl_xor(v, 2, 64);
    v += __shfl_xor(v, 4, 64);
    v += __shfl_xor(v, 8, 64);
    if (m == 0) asum_buf[wv * 64 + (i >> 2) * 16 + q * 4 + (i & 3)] = v;
  }
  lgkm_barrier();
  {
    const int k = t >> 2, c0 = (t & 3) * 32;
    const size_t ob = (size_t)blockIdx.x * (KK * CCH) + k * CCH + c0;
#pragma unroll
    for (int i = 0; i < 8; ++i)
      *(float4*)&vlad_part[ob + i * 4] = *(const float4*)&vt[k * 132 + c0 + i * 4];
  }
  if (t < 64) {
    float s = asum_buf[t] + asum_buf[64 + t] + asum_buf[128 + t] + asum_buf[192 + t];
    asum_part[blockIdx.x * 64 + t] = s;
  }
}

// One wave per (n,k): sum 8 partials, subtract asum*centroid, per-cluster L2 norm.
// Global norm over the 64 unit per-cluster vectors is exactly sqrt(64) -> x0.125.
__global__ __launch_bounds__(256) void netvlad_finish(
    const float* __restrict__ vlad_part, const float* __restrict__ asum_part,
    const float* __restrict__ centroids, float* __restrict__ out) {
  const int t = threadIdx.x;
  const int w = t >> 6, ln = t & 63;
  const int idx = blockIdx.x * 4 + w;  // 0..4095
  const int n = idx >> 6, k = idx & 63;
  const int c = ln * 2;
  float v0 = 0.f, v1 = 0.f;
#pragma unroll
  for (int b = 0; b < BSPLIT; ++b) {
    float2 pv = *(const float2*)&vlad_part[(size_t)(n * BSPLIT + b) * (KK * CCH) + k * CCH + c];
    v0 += pv.x;
    v1 += pv.y;
  }
  float s = 0.f;
#pragma unroll
  for (int b = 0; b < BSPLIT; ++b) s += asum_part[(n * BSPLIT + b) * KK + k];
  float2 ce = *(const float2*)&centroids[k * CCH + c];
  v0 -= s * ce.x;
  v1 -= s * ce.y;
  float ssq = v0 * v0 + v1 * v1;
#pragma unroll
  for (int off = 32; off > 0; off >>= 1) ssq += __shfl_xor(ssq, off, 64);
  float inv = 0.125f / fmaxf(sqrtf(ssq), 1e-12f);
  float2 o;
  o.x = v0 * inv;
  o.y = v1 * inv;
  *(float2*)&out[(size_t)n * (KK * CCH) + k * CCH + c] = o;
}

extern "C" void kernel_launch(void* const* d_in, const int* in_sizes, int n_in,
                              void* d_out, int out_size, void* d_ws, size_t ws_size,
                              hipStream_t stream) {
  const float* x = (const float*)d_in[0];          // (64,128,64,64)
  const float* conv_w = (const float*)d_in[1];     // (64,128)
  const float* conv_b = (const float*)d_in[2];     // (64,)
  const float* centroids = (const float*)d_in[3];  // (64,128)
  float* out = (float*)d_out;                      // (64, 8192)

  float* vlad_part = (float*)d_ws;                                   // 16 MiB
  float* asum_part = vlad_part + (size_t)NNIMG * BSPLIT * KK * CCH;  // 128 KiB

  netvlad_main<<<NNIMG * BSPLIT, 256, 0, stream>>>(x, conv_w, conv_b, vlad_part, asum_part);
  netvlad_finish<<<NNIMG * KK / 4, 256, 0, stream>>>(vlad_part, asum_part, centroids, out);
}

// Round 5
// 229.357 us; speedup vs baseline: 1.2017x; 1.0366x over previous
//
#include <hip/hip_runtime.h>
#include <math.h>

// NetVLAD, pure-bf16 MFMA, 2-wave blocks, 4 blocks/CU, atomic reduction.
// Sizes fixed: N=64, C=128, P=4096, K=64.
#define NNIMG 64
#define CCH 128
#define KK 64
#define PP 4096
#define BSPLIT 16
#define PB (PP / BSPLIT)   // 256 pixels per block
#define PC 32              // pixels per chunk
#define NCHUNK (PB / PC)   // 8

typedef __attribute__((ext_vector_type(8))) short short8;
typedef __attribute__((ext_vector_type(4))) float f32x4;

__device__ __forceinline__ unsigned short bf16_rtne(float f) {
  unsigned u = __float_as_uint(f);
  unsigned r = u + 0x7FFFu + ((u >> 16) & 1u);
  return (unsigned short)(r >> 16);
}
__device__ __forceinline__ float bf16_tof(unsigned short h) {
  return __uint_as_float(((unsigned)h) << 16);
}

// barrier with LDS visibility, vmcnt stays open (DMA in flight)
__device__ __forceinline__ void lgkm_barrier() {
  __asm__ volatile("s_waitcnt lgkmcnt(0)\n\ts_barrier" ::: "memory");
}
// chunk-top barrier: DMA landed + all LDS drained
__device__ __forceinline__ void vm_barrier() {
  __asm__ volatile("s_waitcnt vmcnt(0) lgkmcnt(0)\n\ts_barrier" ::: "memory");
}

__device__ __forceinline__ void load_to_lds16(const float* g, float* l) {
  __builtin_amdgcn_global_load_lds((const __attribute__((address_space(1))) void*)g,
                                   (__attribute__((address_space(3))) void*)l, 16, 0, 0);
}

// LDS (30464 B):
//  xraw : f32 [c=128][p=32] contiguous, DMA dest                       16384 B
//  pc   : u32 [p=32][e=64, stride 66]; e=c>>1, u32 = bf16(x[2e])|bf16(x[2e+1])<<16
//         bank(2p+e): stage-write & G1-read & G2-gather all <=2-way     8448 B
//  a_lds: u16 [k=64][p stride 40] assignments bf16 (b128-aligned reads) 5120 B
//  asum_buf: f32 [2][64]                                                 512 B
__global__ __launch_bounds__(128, 2) void netvlad_main(
    const float* __restrict__ x, const float* __restrict__ conv_w,
    const float* __restrict__ conv_b, float* __restrict__ vg,
    float* __restrict__ ag) {
  __shared__ __align__(16) float xraw[CCH * PC];
  __shared__ __align__(16) unsigned int pc[PC * 66];
  __shared__ __align__(16) unsigned short a_lds[KK * 40];
  __shared__ float asum_buf[2 * KK];

  const int t = threadIdx.x;
  const int lane = t & 63;
  const int wv = t >> 6;      // wave 0..1
  const int m = lane & 15;
  const int q = lane >> 4;

  const int n = blockIdx.x >> 4;
  const int blk = blockIdx.x & 15;
  const float* xbase = x + (size_t)n * CCH * PP + blk * PB;

  // DMA one chunk: wave wv covers c rows wv*64..wv*64+63 via 8 insts (8 rows each).
  const int dma_c = (lane >> 3);        // row within 8-row group
  const int dma_p = (lane & 7) * 4;     // 16B per lane
  auto issue_dma = [&](int ch) {
#pragma unroll
    for (int i = 0; i < 8; ++i) {
      int rowbase = wv * 64 + i * 8;
      const float* g = xbase + (size_t)(rowbase + dma_c) * PP + ch * PC + dma_p;
      load_to_lds16(g, &xraw[rowbase * PC]);
    }
  };

  issue_dma(0);  // prologue prefetch; covered by setup below

  // ---- W hi-only fragments: A[m = k-row][kdim = c], 4kt x 4cs, 64 VGPRs ----
  short8 Whi[4][4];
#pragma unroll
  for (int kt = 0; kt < 4; ++kt)
#pragma unroll
    for (int cs = 0; cs < 4; ++cs) {
      const float* wp = conv_w + (kt * 16 + m) * CCH + cs * 32 + q * 8;
      float4 wa = *(const float4*)wp;
      float4 wb = *(const float4*)(wp + 4);
      float fv[8] = {wa.x, wa.y, wa.z, wa.w, wb.x, wb.y, wb.z, wb.w};
      short8 h;
#pragma unroll
      for (int j = 0; j < 8; ++j) h[j] = (short)bf16_rtne(fv[j]);
      Whi[kt][cs] = h;
    }
  // bias: lane's 16 k-values
  float b_regs[4][4];
#pragma unroll
  for (int kt = 0; kt < 4; ++kt)
#pragma unroll
    for (int r = 0; r < 4; ++r) b_regs[kt][r] = conv_b[kt * 16 + q * 4 + r];

  f32x4 vacc[4][4];  // V[k: 4 kt][c: 4 ct within wave's 64-c half]
#pragma unroll
  for (int kt = 0; kt < 4; ++kt)
#pragma unroll
    for (int ct = 0; ct < 4; ++ct) vacc[kt][ct] = (f32x4){0.f, 0.f, 0.f, 0.f};
  float asum_acc[16];
#pragma unroll
  for (int i = 0; i < 16; ++i) asum_acc[i] = 0.f;

  const int sp = lane & 31;             // stage: p
  const int sh = lane >> 5;             // stage: e low bit
  const int prow = wv * 16 + m;         // GEMM1: lane's pixel column (0..31)
  const unsigned sel_hi = 0x07060302u;  // perm: hi16 of each src
  const unsigned sel_g2 = (m & 1) ? 0x07060302u : 0x05040100u;

#pragma unroll 1
  for (int ch = 0; ch < NCHUNK; ++ch) {
    vm_barrier();  // DMA(ch) landed everywhere; all prior LDS reads drained

    // ---- stage: xraw -> bf16 pair-pack -> pc[p][e] (all accesses <=2-way) ----
    {
      const float* xr = xraw + (4 * wv + 2 * sh) * PC + sp;
      const int pbase = sp * 66 + 2 * wv + sh;
#pragma unroll
      for (int i = 0; i < 16; ++i) {
        float x0 = xr[i * (8 * PC)];
        float x1 = xr[i * (8 * PC) + PC];
        pc[pbase + 4 * i] =
            __builtin_amdgcn_perm(__float_as_uint(x1), __float_as_uint(x0), sel_hi);
      }
    }
    lgkm_barrier();  // B1: pc published; xraw reads drained

    if (ch < NCHUNK - 1) issue_dma(ch + 1);  // lands during GEMMs

    // ---- GEMM1: L[64 k][p=prow] = Whi . x_hi, K=128 over 4 cs ----
    f32x4 acc1[4];
#pragma unroll
    for (int kt = 0; kt < 4; ++kt)
      acc1[kt] = (f32x4){b_regs[kt][0], b_regs[kt][1], b_regs[kt][2], b_regs[kt][3]};
    const unsigned int* pcrow = pc + prow * 66;
#pragma unroll
    for (int cs = 0; cs < 4; ++cs) {
      uint2 u01 = *(const uint2*)&pcrow[16 * cs + 4 * q];
      uint2 u23 = *(const uint2*)&pcrow[16 * cs + 4 * q + 2];
      unsigned hs[4] = {u01.x, u01.y, u23.x, u23.y};
      short8 Bf;
      __builtin_memcpy(&Bf, hs, 16);
#pragma unroll
      for (int kt = 0; kt < 4; ++kt)
        acc1[kt] = __builtin_amdgcn_mfma_f32_16x16x32_bf16(Whi[kt][cs], Bf, acc1[kt], 0, 0, 0);
    }

    // ---- softmax over k (register-resident; lane holds 16 of 64 k) ----
    float ssum = 0.f;
#pragma unroll
    for (int kt = 0; kt < 4; ++kt)
#pragma unroll
      for (int r = 0; r < 4; ++r) {
        float e = __expf(acc1[kt][r]);
        acc1[kt][r] = e;
        ssum += e;
      }
    ssum += __shfl_xor(ssum, 16, 64);
    ssum += __shfl_xor(ssum, 32, 64);
    float inv = 1.0f / ssum;
#pragma unroll
    for (int kt = 0; kt < 4; ++kt)
#pragma unroll
      for (int r = 0; r < 4; ++r) {
        float a = acc1[kt][r] * inv;
        unsigned short h = bf16_rtne(a);
        asum_acc[kt * 4 + r] += bf16_tof(h);  // consistent with GEMM2's operand
        a_lds[(kt * 16 + q * 4 + r) * 40 + prow] = h;
      }
    lgkm_barrier();  // B2: a_lds published

    // ---- GEMM2: V[k][c] += A[k][p] . x_hi^T[p][c], K=32 one shot ----
    short8 Af[4];
#pragma unroll
    for (int kt = 0; kt < 4; ++kt)
      Af[kt] = *(const short8*)&a_lds[(kt * 16 + m) * 40 + q * 8];
#pragma unroll
    for (int ct = 0; ct < 4; ++ct) {
      const int ebase = wv * 32 + ct * 8 + (m >> 1);
      unsigned g[8];
#pragma unroll
      for (int j = 0; j < 8; ++j) g[j] = pc[(q * 8 + j) * 66 + ebase];
      unsigned hs[4];
#pragma unroll
      for (int i = 0; i < 4; ++i)
        hs[i] = __builtin_amdgcn_perm(g[2 * i + 1], g[2 * i], sel_g2);
      short8 Bf;
      __builtin_memcpy(&Bf, hs, 16);
#pragma unroll
      for (int kt = 0; kt < 4; ++kt)
        vacc[kt][ct] = __builtin_amdgcn_mfma_f32_16x16x32_bf16(Af[kt], Bf, vacc[kt][ct], 0, 0, 0);
    }
  }

  // ---- epilogue: atomic-accumulate V into per-image buffer (64B segments) ----
  float* vrow = vg + (size_t)n * (KK * CCH);
#pragma unroll
  for (int kt = 0; kt < 4; ++kt)
#pragma unroll
    for (int ct = 0; ct < 4; ++ct)
#pragma unroll
      for (int r = 0; r < 4; ++r)
        atomicAdd(&vrow[(kt * 16 + q * 4 + r) * CCH + wv * 64 + ct * 16 + m],
                  vacc[kt][ct][r]);
  // asum: reduce over m-lanes, one atomic per (q,kt,r) from m==0
#pragma unroll
  for (int i = 0; i < 16; ++i) {
    float v = asum_acc[i];
    v += __shfl_xor(v, 1, 64);
    v += __shfl_xor(v, 2, 64);
    v += __shfl_xor(v, 4, 64);
    v += __shfl_xor(v, 8, 64);
    if (m == 0) asum_buf[wv * 64 + (i >> 2) * 16 + q * 4 + (i & 3)] = v;
  }
  lgkm_barrier();
  if (t < KK) atomicAdd(&ag[n * KK + t], asum_buf[t] + asum_buf[KK + t]);
}

// One wave per (n,k): subtract asum*centroid, per-cluster L2 norm.
// Global norm over 64 unit per-cluster vectors is exactly sqrt(64) -> x0.125.
__global__ __launch_bounds__(256) void netvlad_finish(
    const float* __restrict__ vg, const float* __restrict__ ag,
    const float* __restrict__ centroids, float* __restrict__ out) {
  const int t = threadIdx.x;
  const int w = t >> 6, ln = t & 63;
  const int idx = blockIdx.x * 4 + w;  // 0..4095
  const int n = idx >> 6, k = idx & 63;
  const int c = ln * 2;
  float2 v = *(const float2*)&vg[(size_t)(n * KK + k) * CCH + c];
  float s = ag[n * KK + k];
  float2 ce = *(const float2*)&centroids[k * CCH + c];
  float v0 = v.x - s * ce.x;
  float v1 = v.y - s * ce.y;
  float ssq = v0 * v0 + v1 * v1;
#pragma unroll
  for (int off = 32; off > 0; off >>= 1) ssq += __shfl_xor(ssq, off, 64);
  float inv = 0.125f / fmaxf(sqrtf(ssq), 1e-12f);
  float2 o;
  o.x = v0 * inv;
  o.y = v1 * inv;
  *(float2*)&out[(size_t)n * (KK * CCH) + k * CCH + c] = o;
}

extern "C" void kernel_launch(void* const* d_in, const int* in_sizes, int n_in,
                              void* d_out, int out_size, void* d_ws, size_t ws_size,
                              hipStream_t stream) {
  const float* x = (const float*)d_in[0];          // (64,128,64,64)
  const float* conv_w = (const float*)d_in[1];     // (64,128)
  const float* conv_b = (const float*)d_in[2];     // (64,)
  const float* centroids = (const float*)d_in[3];  // (64,128)
  float* out = (float*)d_out;                      // (64, 8192)

  float* vg = (float*)d_ws;                        // 64*64*128 f32 = 2 MiB
  float* ag = vg + (size_t)NNIMG * KK * CCH;       // 64*64 f32 = 16 KiB
  const size_t zbytes = ((size_t)NNIMG * KK * CCH + NNIMG * KK) * sizeof(float);

  hipMemsetAsync(d_ws, 0, zbytes, stream);  // atomic accumulators start at 0
  netvlad_main<<<NNIMG * BSPLIT, 128, 0, stream>>>(x, conv_w, conv_b, vg, ag);
  netvlad_finish<<<NNIMG * KK / 4, 256, 0, stream>>>(vg, ag, centroids, out);
}